// Round 1
// baseline (292.578 us; speedup 1.0000x reference)
//
#include <hip/hip_runtime.h>
#include <hip/hip_bf16.h>

// Problem constants (fixed by setup_inputs): B=2, H=W=64, T=4096, C=192
#define BATCH 2
#define HH 64
#define WW 64
#define TLEN 4096
#define CC 192
#define HP 68          // H + 2*PAD, PAD=2
#define PADC 2

__device__ __constant__ float PRF_X[16] = {-2,-2,-2,-2, -2,-1,0,1, 2,2,2,2, -1,0,1,2};
__device__ __constant__ float PRF_Y[16] = {-2,-1,0,1, 2,2,2,2, -1,0,1,2, -2,-2,-2,-2};

// ---------------- build xx (q_shift output) ----------------
__global__ __launch_bounds__(256) void k_build_xx(const float* __restrict__ x,
                                                  float* __restrict__ XX) {
    int idx = blockIdx.x * 256 + threadIdx.x;
    if (idx >= BATCH * TLEN * CC) return;
    int tg = idx / CC;          // b*T + t
    int c  = idx - tg * CC;
    int t  = tg & (TLEN - 1);
    int i  = t >> 6;
    int j  = t & 63;
    int g  = c / 48;
    float v;
    if (g == 0)      v = (j > 0)  ? x[idx - CC]        : 0.0f;  // shift right in W
    else if (g == 1) v = (j < 63) ? x[idx + CC]        : 0.0f;  // shift left
    else if (g == 2) v = (i > 0)  ? x[idx - 64 * CC]   : 0.0f;  // shift down in H
    else             v = (i < 63) ? x[idx + 64 * CC]   : 0.0f;  // shift up
    XX[idx] = v;
}

// ---------------- build concatenated, mix-scaled weights ----------------
// Wcat (384 x 576): rows 0..191 = mix[c]*W[c,:], rows 192..383 = (1-mix[c])*W[c,:]
// col blocks: [0,192)=Wk/mix_k  [192,384)=Wv/mix_v  [384,576)=Wr/mix_r
__global__ __launch_bounds__(256) void k_build_wcat(const float* __restrict__ Wk,
                                                    const float* __restrict__ Wv,
                                                    const float* __restrict__ Wr,
                                                    const float* __restrict__ mk,
                                                    const float* __restrict__ mv,
                                                    const float* __restrict__ mr,
                                                    float* __restrict__ Wcat) {
    int idx = blockIdx.x * 256 + threadIdx.x;
    if (idx >= 384 * 576) return;
    int r  = idx / 576;
    int jj = idx - r * 576;
    int cb  = jj / CC;
    int col = jj - cb * CC;
    const float* W   = (cb == 0) ? Wk : (cb == 1) ? Wv : Wr;
    const float* mix = (cb == 0) ? mk : (cb == 1) ? mv : mr;
    float v;
    if (r < CC) v = mix[r] * W[r * CC + col];
    else        v = (1.0f - mix[r - CC]) * W[(r - CC) * CC + col];
    Wcat[idx] = v;
}

// ---------------- fp32 tiled GEMM ----------------
// C[M,N] = A[M,K] @ B[K,N].  A is split into two halves along K, each with row
// stride 192: k<192 reads A0, k>=192 reads A1 (GEMM1: A0=x, A1=xx; GEMM2: A0=A1=P).
// Epilogue: sigmoid applied to columns >= sig_start.
__global__ __launch_bounds__(256) void k_gemm(const float* __restrict__ A0,
                                              const float* __restrict__ A1,
                                              const float* __restrict__ B,
                                              float* __restrict__ C,
                                              int M, int N, int K, int sig_start) {
    __shared__ float As[16][68];   // [k][m], padded to 68 for bank/alignment
    __shared__ float Bs[16][68];   // [k][n]
    int tid = threadIdx.x;
    int bm = blockIdx.y * 64;
    int bn = blockIdx.x * 64;
    int tx = tid & 15, ty = tid >> 4;
    int ar  = tid >> 2;            // A-load row 0..63
    int ak  = (tid & 3) << 2;      // A-load k offset (float4)
    int bk  = tid >> 4;            // B-load k 0..15
    int bn4 = (tid & 15) << 2;     // B-load col offset (float4)

    float acc[4][4] = {{0.f}};

    for (int k0 = 0; k0 < K; k0 += 16) {
        const float* Ab = (k0 < CC) ? A0 : A1;
        int kloc = (k0 < CC) ? k0 : k0 - CC;
        float4 av = *(const float4*)(Ab + (size_t)(bm + ar) * CC + kloc + ak);
        float4 bv = *(const float4*)(B + (size_t)(k0 + bk) * N + bn + bn4);
        __syncthreads();
        As[ak + 0][ar] = av.x; As[ak + 1][ar] = av.y;
        As[ak + 2][ar] = av.z; As[ak + 3][ar] = av.w;
        *(float4*)(&Bs[bk][bn4]) = bv;
        __syncthreads();
#pragma unroll
        for (int kk = 0; kk < 16; ++kk) {
            float4 a4 = *(const float4*)(&As[kk][ty << 2]);
            float4 b4 = *(const float4*)(&Bs[kk][tx << 2]);
            float avr[4] = {a4.x, a4.y, a4.z, a4.w};
            float bvr[4] = {b4.x, b4.y, b4.z, b4.w};
#pragma unroll
            for (int ii = 0; ii < 4; ++ii)
#pragma unroll
                for (int jj = 0; jj < 4; ++jj)
                    acc[ii][jj] = fmaf(avr[ii], bvr[jj], acc[ii][jj]);
        }
    }
#pragma unroll
    for (int ii = 0; ii < 4; ++ii) {
        int row = bm + (ty << 2) + ii;
#pragma unroll
        for (int jj = 0; jj < 4; ++jj) {
            int col = bn + (tx << 2) + jj;
            float v = acc[ii][jj];
            if (col >= sig_start) v = 1.0f / (1.0f + expf(-v));
            C[(size_t)row * N + col] = v;
        }
    }
}

// ---------------- band_est: channel-summed 7-tap convs + BN + sigmoid*2 ----------------
// one block per pixel (b,i,j); 192 threads, one per channel; reduce 4 sums.
__global__ __launch_bounds__(192) void k_band(const float* __restrict__ x,
                                              const float* __restrict__ cvw,
                                              const float* __restrict__ cvb,
                                              const float* __restrict__ bns_v,
                                              const float* __restrict__ bnb_v,
                                              const float* __restrict__ chw,
                                              const float* __restrict__ chb,
                                              const float* __restrict__ bns_h,
                                              const float* __restrict__ bnb_h,
                                              float* __restrict__ gb) {
    int pixg = blockIdx.x;
    int b   = pixg >> 12;
    int pix = pixg & 4095;
    int i = pix >> 6, j = pix & 63;
    int c = threadIdx.x;
    size_t xbase = (size_t)b * TLEN * CC;

    float sv0 = 0.f, sv1 = 0.f, sh0 = 0.f, sh1 = 0.f;
#pragma unroll
    for (int t = 0; t < 7; ++t) {
        int ii = i + t - 3;
        if (ii >= 0 && ii < HH) {
            float xv = x[xbase + (size_t)(ii * WW + j) * CC + c];
            sv0 = fmaf(xv, cvw[(0 * CC + c) * 7 + t], sv0);
            sv1 = fmaf(xv, cvw[(1 * CC + c) * 7 + t], sv1);
        }
        int jj = j + t - 3;
        if (jj >= 0 && jj < WW) {
            float xh = x[xbase + (size_t)(i * WW + jj) * CC + c];
            sh0 = fmaf(xh, chw[(0 * CC + c) * 7 + t], sh0);
            sh1 = fmaf(xh, chw[(1 * CC + c) * 7 + t], sh1);
        }
    }
    __shared__ float red[4][CC];
    red[0][c] = sv0; red[1][c] = sv1; red[2][c] = sh0; red[3][c] = sh1;
    __syncthreads();
    if (c < 4) {
        float s = 0.f;
        for (int q = 0; q < CC; ++q) s += red[c][q];
        const float inv = 0.9999950000374997f;   // 1/sqrt(1+1e-5) in f32
        float bias, sc, sh;
        if (c < 2) { bias = cvb[c];     sc = bns_v[c];     sh = bnb_v[c]; }
        else       { bias = chb[c - 2]; sc = bns_h[c - 2]; sh = bnb_h[c - 2]; }
        float g = (s + bias) * (sc * inv) + sh;
        g = 2.0f / (1.0f + expf(-g));            // sigmoid * (GB_MAX-1)
        gb[(size_t)(b * 4 + c) * 4096 + pix] = g;
    }
}

// ---------------- ada_peak gather, added into the v-section of Z ----------------
__global__ __launch_bounds__(192) void k_peak(const float* __restrict__ x,
                                              const float* __restrict__ gb,
                                              float* __restrict__ Z) {
    int pixg = blockIdx.x;
    int b   = pixg >> 12;
    int pix = pixg & 4095;
    int i = pix >> 6, j = pix & 63;
    int c = threadIdx.x;

    __shared__ int   l_lt[16], l_rb[16];
    __shared__ float l_glt[16], l_grb[16];

    if (c < 16) {
        int n = c, blk = n >> 2;
        size_t gbase = (size_t)b * 4 * 4096 + pix;
        float g0 = gb[gbase + 0 * 4096];
        float g1 = gb[gbase + 1 * 4096];
        float g2 = gb[gbase + 2 * 4096];
        float g3 = gb[gbase + 3 * 4096];
        float mx = (blk == 0) ? -g0 : (blk == 2) ? g1 : 0.0f;
        float my = (blk == 1) ?  g3 : (blk == 3) ? -g2 : 0.0f;
        float px = (float)(i + PADC) + PRF_X[n] + mx;
        float py = (float)(j + PADC) + PRF_Y[n] + my;
        float flx = floorf(px), fly = floorf(py);
        float qltx = fminf(fmaxf(flx, 0.f), 67.f);
        float qlty = fminf(fmaxf(fly, 0.f), 67.f);
        float qrbx = fminf(fmaxf(flx + 1.f, 0.f), 67.f);
        float qrby = fminf(fmaxf(fly + 1.f, 0.f), 67.f);
        float pxc = fminf(fmaxf(px, 0.f), 67.f);
        float pyc = fminf(fmaxf(py, 0.f), 67.f);
        float glt = (1.f + (qltx - pxc)) * (1.f + (qlty - pyc));
        float grb = (1.f - (qrbx - pxc)) * (1.f - (qrby - pyc));
        // map padded coords to original image with edge clamp
        int sltx = min(max((int)qltx - PADC, 0), 63);
        int slty = min(max((int)qlty - PADC, 0), 63);
        int srbx = min(max((int)qrbx - PADC, 0), 63);
        int srby = min(max((int)qrby - PADC, 0), 63);
        l_lt[n] = sltx * 64 + slty;
        l_rb[n] = srbx * 64 + srby;
        l_glt[n] = glt;
        l_grb[n] = grb;
    }
    __syncthreads();

    size_t xbase = (size_t)b * TLEN * CC;
    float acc = 0.f;
#pragma unroll
    for (int n = 0; n < 16; ++n) {
        acc = fmaf(l_glt[n], x[xbase + (size_t)l_lt[n] * CC + c], acc);
        acc = fmaf(l_grb[n], x[xbase + (size_t)l_rb[n] * CC + c], acc);
    }
    float peak = x[xbase + (size_t)pix * CC + c] - acc * 0.0625f;
    size_t zi = ((size_t)b * TLEN + pix) * 576 + CC + c;   // v-section
    Z[zi] += peak;
}

// ---------------- bi_wkv via chunked associative scan ----------------
// one block per (b,c) chain; 256 threads x 16-element chunks.
__global__ __launch_bounds__(256) void k_wkv(const float* __restrict__ Z,
                                             float* __restrict__ P,
                                             const float* __restrict__ sd,
                                             const float* __restrict__ sf) {
    const int NTH = 256, CH = 16;
    int c = blockIdx.x % CC;
    int b = blockIdx.x / CC;
    const float w = sd[c] / 4096.0f;
    const float u = sf[c] / 4096.0f;

    __shared__ float ks[TLEN];
    __shared__ float vs[TLEN];
    __shared__ float s_m[NTH], s_a[NTH], s_b[NTH], s_L[NTH];

    int tid = threadIdx.x;
    size_t rowbase = (size_t)b * TLEN;
    for (int t = tid; t < TLEN; t += NTH) {
        size_t zi = (rowbase + t) * 576;
        ks[t] = Z[zi + c];
        vs[t] = Z[zi + CC + c];
    }
    __syncthreads();

    int s = tid * CH;
    // ---- forward local chunk summary (scores ref: chunk end)
    float m = -1e38f, a = 0.f, bb = 0.f;
#pragma unroll
    for (int jj = 0; jj < CH; ++jj) {
        float kt = ks[s + jj], vt = vs[s + jj];
        float m2 = fmaxf(m - w, kt);
        float e1 = expf(m - w - m2);
        float e2 = expf(kt - m2);
        a = e1 * a + e2;
        bb = e1 * bb + e2 * vt;
        m = m2;
    }
    // ---- inclusive prefix scan of summaries (combine decays LEFT by right.L*w)
    s_m[tid] = m; s_a[tid] = a; s_b[tid] = bb; s_L[tid] = (float)CH;
    float L = (float)CH;
    for (int d = 1; d < NTH; d <<= 1) {
        __syncthreads();
        float pm = 0, pa = 0, pb = 0, pL = 0;
        bool has = (tid >= d);
        if (has) { pm = s_m[tid - d]; pa = s_a[tid - d]; pb = s_b[tid - d]; pL = s_L[tid - d]; }
        __syncthreads();
        if (has) {
            float pdec = pm - L * w;
            float m2 = fmaxf(pdec, m);
            float e1 = expf(pdec - m2);
            float e2 = expf(m - m2);
            a  = e1 * pa + e2 * a;
            bb = e1 * pb + e2 * bb;
            m = m2; L += pL;
            s_m[tid] = m; s_a[tid] = a; s_b[tid] = bb; s_L[tid] = L;
        }
    }
    __syncthreads();
    float fm = -1e38f, fa = 0.f, fb = 0.f;
    if (tid > 0) { fm = s_m[tid - 1]; fa = s_a[tid - 1]; fb = s_b[tid - 1]; }
    __syncthreads();

    // ---- backward local chunk summary (scores ref: chunk start)
    m = -1e38f; a = 0.f; bb = 0.f;
#pragma unroll
    for (int jj = CH - 1; jj >= 0; --jj) {
        float kt = ks[s + jj], vt = vs[s + jj];
        float m2 = fmaxf(m - w, kt);
        float e1 = expf(m - w - m2);
        float e2 = expf(kt - m2);
        a = e1 * a + e2;
        bb = e1 * bb + e2 * vt;
        m = m2;
    }
    // ---- inclusive suffix scan (combine decays FAR by near.L*w)
    s_m[tid] = m; s_a[tid] = a; s_b[tid] = bb; s_L[tid] = (float)CH;
    L = (float)CH;
    for (int d = 1; d < NTH; d <<= 1) {
        __syncthreads();
        float pm = 0, pa = 0, pb = 0, pL = 0;
        bool has = (tid + d) < NTH;
        if (has) { pm = s_m[tid + d]; pa = s_a[tid + d]; pb = s_b[tid + d]; pL = s_L[tid + d]; }
        __syncthreads();
        if (has) {
            float pdec = pm - L * w;
            float m2 = fmaxf(m, pdec);
            float e1 = expf(m - m2);
            float e2 = expf(pdec - m2);
            a  = e1 * a + e2 * pa;
            bb = e1 * bb + e2 * pb;
            m = m2; L += pL;
            s_m[tid] = m; s_a[tid] = a; s_b[tid] = bb; s_L[tid] = L;
        }
    }
    __syncthreads();
    float bm = -1e38f, ba = 0.f, bbv = 0.f;
    if (tid < NTH - 1) { bm = s_m[tid + 1]; ba = s_a[tid + 1]; bbv = s_b[tid + 1]; }

    // ---- backward re-scan: record per-element backward states in registers
    float em[CH], ea[CH], eb[CH];
    m = bm; a = ba; bb = bbv;
#pragma unroll
    for (int jj = CH - 1; jj >= 0; --jj) {
        em[jj] = m; ea[jj] = a; eb[jj] = bb;
        float kt = ks[s + jj], vt = vs[s + jj];
        float m2 = fmaxf(m - w, kt);
        float e1 = expf(m - w - m2);
        float e2 = expf(kt - m2);
        a = e1 * a + e2;
        bb = e1 * bb + e2 * vt;
        m = m2;
    }

    // ---- forward re-scan + combine + output P = sr * y
    m = fm; a = fa; bb = fb;
#pragma unroll
    for (int jj = 0; jj < CH; ++jj) {
        int t = s + jj;
        float kt = ks[t], vt = vs[t];
        float ms = u + kt;
        float M = fmaxf(fmaxf(m, em[jj]), ms);
        float ef  = expf(m - M);
        float ebk = expf(em[jj] - M);
        float es  = expf(ms - M);
        float num = ef * bb + ebk * eb[jj] + es * vt;
        float den = ef * a + ebk * ea[jj] + es;
        float y = num / den;
        size_t zi = (rowbase + t) * 576;
        float sr = Z[zi + 2 * CC + c];
        P[(rowbase + t) * CC + c] = sr * y;
        float m2 = fmaxf(m - w, kt);
        float e1 = expf(m - w - m2);
        float e2 = expf(kt - m2);
        a = e1 * a + e2;
        bb = e1 * bb + e2 * vt;
        m = m2;
    }
}

extern "C" void kernel_launch(void* const* d_in, const int* in_sizes, int n_in,
                              void* d_out, int out_size, void* d_ws, size_t ws_size,
                              hipStream_t stream) {
    const float* x     = (const float*)d_in[0];
    const float* mix_k = (const float*)d_in[3];
    const float* mix_v = (const float*)d_in[4];
    const float* mix_r = (const float*)d_in[5];
    const float* Wk    = (const float*)d_in[6];
    const float* Wv    = (const float*)d_in[7];
    const float* Wr    = (const float*)d_in[8];
    const float* Wo    = (const float*)d_in[9];
    const float* sd    = (const float*)d_in[10];
    const float* sf    = (const float*)d_in[11];
    const float* cvw   = (const float*)d_in[12];
    const float* cvb   = (const float*)d_in[13];
    const float* bns_v = (const float*)d_in[14];
    const float* bnb_v = (const float*)d_in[15];
    const float* chw   = (const float*)d_in[16];
    const float* chb   = (const float*)d_in[17];
    const float* bns_h = (const float*)d_in[18];
    const float* bnb_h = (const float*)d_in[19];
    float* out = (float*)d_out;
    float* ws  = (float*)d_ws;

    // workspace layout (floats)
    float* XX   = ws;                 // 1,572,864
    float* Z    = ws + 1572864;       // 4,718,592  (8192 x 576: k|v|sr)
    float* Wcat = ws + 6291456;       //   221,184  (384 x 576)
    float* gbuf = ws + 6512640;       //    32,768  (2 x 4 x 4096)
    float* P    = ws + 6545408;       // 1,572,864  (8192 x 192)

    k_build_xx<<<6144, 256, 0, stream>>>(x, XX);
    k_build_wcat<<<864, 256, 0, stream>>>(Wk, Wv, Wr, mix_k, mix_v, mix_r, Wcat);
    // Z = [x|xx] @ Wcat, sigmoid on cols >= 384
    k_gemm<<<dim3(9, 128), 256, 0, stream>>>(x, XX, Wcat, Z, 8192, 576, 384, 384);
    k_band<<<8192, 192, 0, stream>>>(x, cvw, cvb, bns_v, bnb_v, chw, chb, bns_h, bnb_h, gbuf);
    k_peak<<<8192, 192, 0, stream>>>(x, gbuf, Z);
    k_wkv<<<384, 256, 0, stream>>>(Z, P, sd, sf);
    // out = P @ Wo
    k_gemm<<<dim3(3, 128), 256, 0, stream>>>(P, P, Wo, out, 8192, CC, CC, 1 << 30);
}